// Round 1
// baseline (568.434 us; speedup 1.0000x reference)
//
#include <hip/hip_runtime.h>
#include <stdint.h>

// Problem constants (from reference): N=4096, B=32, LATENT=16, UNITS=64,
// NNZ=65536, K=2, M=5.
#define NN    4096
#define BB    32
#define NNZE  65536
#define WA    512      // LATENT*B  (pass-A diffusion width)
#define WB    2048     // UNITS*B   (pass-B diffusion width)

// ---------- bf16 helpers (OCP bf16 = f32 truncation w/ RNE) ----------
__device__ __forceinline__ float bf2f(unsigned int h) {
    union { unsigned int u; float f; } c; c.u = h << 16; return c.f;
}
__device__ __forceinline__ unsigned int f2bf(float f) {
    union { float ff; unsigned int u; } c; c.ff = f;
    return (c.u + 0x7fffu + ((c.u >> 16) & 1u)) >> 16;
}

// ---------- CSR build ----------
__global__ void hist_kernel(const int* __restrict__ rows, int* __restrict__ cnt) {
    int e = blockIdx.x * blockDim.x + threadIdx.x;
    if (e < NNZE) atomicAdd(&cnt[rows[e]], 1);
}

// 4096-entry exclusive scan, single block of 256 threads. cnt may alias cur.
__global__ void scan_kernel(const int* cnt, int* rp, int* cur) {
    __shared__ int part[256];
    int t = threadIdx.x;
    int base = t * 16;
    int loc[16];
    int s = 0;
#pragma unroll
    for (int i = 0; i < 16; ++i) { loc[i] = s; s += cnt[base + i]; }
    part[t] = s;
    __syncthreads();
    for (int off = 1; off < 256; off <<= 1) {
        int v = 0;
        if (t >= off) v = part[t - off];
        __syncthreads();
        part[t] += v;
        __syncthreads();
    }
    int excl = (t == 0) ? 0 : part[t - 1];
#pragma unroll
    for (int i = 0; i < 16; ++i) {
        int v = excl + loc[i];
        rp[base + i] = v;
        cur[base + i] = v;
    }
    if (t == 255) rp[4096] = part[255];
}

__global__ void scatter_kernel(const int* __restrict__ rows, int* __restrict__ cur,
                               int* __restrict__ perm) {
    int e = blockIdx.x * blockDim.x + threadIdx.x;
    if (e < NNZE) {
        int pos = atomicAdd(&cur[rows[e]], 1);
        perm[pos] = e;
    }
}

// ---------- pass A: x0[n, f*32+b] = y[b, n*16+f] ----------
__global__ void transposeA_kernel(const float* __restrict__ y, float* __restrict__ x0) {
    int idx = blockIdx.x * blockDim.x + threadIdx.x;   // < N*512
    int n = idx >> 9;
    int rem = idx & 511;
    int f = rem >> 5;
    int b = rem & 31;
    x0[idx] = y[b * (NN * 16) + n * 16 + f];
}

// xout[row,:] = alpha * (S @ xin)[row,:] + beta * xprev[row,:]   (width 512 f32)
__global__ void spmmA_kernel(const float* __restrict__ xin, const float* xprev,
                             float* __restrict__ xout, const int* __restrict__ rp,
                             const int* __restrict__ perm, const int* __restrict__ cols,
                             const float* __restrict__ vals, float alpha, float beta) {
    __shared__ int scol[128];
    __shared__ float sval[128];
    int row = blockIdx.x;
    int t = threadIdx.x;   // 128 threads, 4 cols each (float4)
    int beg = rp[row], end = rp[row + 1];
    float4 acc = make_float4(0.f, 0.f, 0.f, 0.f);
    for (int i0 = beg; i0 < end; i0 += 128) {
        int nn = end - i0; if (nn > 128) nn = 128;
        if (t < nn) { int e = perm[i0 + t]; scol[t] = cols[e]; sval[t] = vals[e]; }
        __syncthreads();
        for (int j = 0; j < nn; ++j) {
            const float4* xr = (const float4*)(xin + (size_t)scol[j] * WA);
            float4 xv = xr[t];
            float v = sval[j];
            acc.x += v * xv.x; acc.y += v * xv.y; acc.z += v * xv.z; acc.w += v * xv.w;
        }
        __syncthreads();
    }
    float4 res;
    res.x = alpha * acc.x; res.y = alpha * acc.y; res.z = alpha * acc.z; res.w = alpha * acc.w;
    if (beta != 0.0f) {
        float4 pv = ((const float4*)(xprev + (size_t)row * WA))[t];
        res.x += beta * pv.x; res.y += beta * pv.y; res.z += beta * pv.z; res.w += beta * pv.w;
    }
    ((float4*)(xout + (size_t)row * WA))[t] = res;
}

// theta_acc[bn,0:16] += x_m @ Wtheta_m ; hid_t[n, f*32+b] += (x_m @ Whid_m)[bn,f]
__global__ void gemmA_kernel(const float* __restrict__ x, const float* __restrict__ Wtheta,
                             const float* __restrict__ Whid, float* __restrict__ theta_acc,
                             float* __restrict__ hid_t, int m) {
    __shared__ float sWt[16 * 16];
    __shared__ float sWh[16 * 64];
    int t = threadIdx.x;   // 128
    for (int i = t; i < 256; i += 128) {
        int f = i >> 4, u = i & 15;
        sWt[i] = Wtheta[(f * 5 + m) * 16 + u];
    }
    for (int i = t; i < 1024; i += 128) {
        int f = i >> 6, u = i & 63;
        sWh[i] = Whid[(f * 5 + m) * 64 + u];
    }
    __syncthreads();
    int b = t & 31, nl = t >> 5;
    int n = blockIdx.x * 4 + nl;
    float xv[16];
    const float* xp = x + (size_t)n * WA + b;
#pragma unroll
    for (int f = 0; f < 16; ++f) xv[f] = xp[f * 32];
    float tacc[16];
    float hacc[64];
#pragma unroll
    for (int u = 0; u < 16; ++u) tacc[u] = 0.f;
#pragma unroll
    for (int u = 0; u < 64; ++u) hacc[u] = 0.f;
#pragma unroll
    for (int f = 0; f < 16; ++f) {
        float xf = xv[f];
#pragma unroll
        for (int u = 0; u < 16; ++u) tacc[u] += xf * sWt[f * 16 + u];
#pragma unroll
        for (int u = 0; u < 64; ++u) hacc[u] += xf * sWh[f * 64 + u];
    }
    size_t bn = (size_t)b * NN + n;
    float4* tp = (float4*)(theta_acc + bn * 16);
#pragma unroll
    for (int g = 0; g < 4; ++g) {
        float4 v = tp[g];
        v.x += tacc[g * 4 + 0]; v.y += tacc[g * 4 + 1];
        v.z += tacc[g * 4 + 2]; v.w += tacc[g * 4 + 3];
        tp[g] = v;
    }
    float* hp = hid_t + (size_t)n * WB + b;
#pragma unroll
    for (int f = 0; f < 64; ++f) hp[f * 32] += hacc[f];
}

// x0b[idx] = bf16( tanh(hid_t[idx] + b_hid[f]) ),  f = (idx>>5)&63
__global__ void actB_kernel(const float* __restrict__ hid_t, const float* __restrict__ b_hid,
                            unsigned short* __restrict__ x0b) {
    int idx = blockIdx.x * blockDim.x + threadIdx.x;   // < N*2048
    int f = (idx >> 5) & 63;
    x0b[idx] = (unsigned short)f2bf(tanhf(hid_t[idx] + b_hid[f]));
}

// bf16 SpMM, width 2048: xout = alpha * (S @ xin) + beta * xprev
__global__ void spmmB_kernel(const unsigned short* __restrict__ xin, const unsigned short* xprev,
                             unsigned short* __restrict__ xout, const int* __restrict__ rp,
                             const int* __restrict__ perm, const int* __restrict__ cols,
                             const float* __restrict__ vals, float alpha, float beta) {
    __shared__ int scol[256];
    __shared__ float sval[256];
    int row = blockIdx.x;
    int t = threadIdx.x;   // 256 threads, 8 bf16 cols each (uint4)
    int beg = rp[row], end = rp[row + 1];
    float acc[8];
#pragma unroll
    for (int k = 0; k < 8; ++k) acc[k] = 0.f;
    for (int i0 = beg; i0 < end; i0 += 256) {
        int nn = end - i0; if (nn > 256) nn = 256;
        if (t < nn) { int e = perm[i0 + t]; scol[t] = cols[e]; sval[t] = vals[e]; }
        __syncthreads();
        for (int j = 0; j < nn; ++j) {
            const uint4* xr = (const uint4*)(xin + (size_t)scol[j] * WB);
            uint4 xv = xr[t];
            float v = sval[j];
            acc[0] += v * bf2f(xv.x & 0xffffu);
            acc[1] += v * bf2f(xv.x >> 16);
            acc[2] += v * bf2f(xv.y & 0xffffu);
            acc[3] += v * bf2f(xv.y >> 16);
            acc[4] += v * bf2f(xv.z & 0xffffu);
            acc[5] += v * bf2f(xv.z >> 16);
            acc[6] += v * bf2f(xv.w & 0xffffu);
            acc[7] += v * bf2f(xv.w >> 16);
        }
        __syncthreads();
    }
    float r[8];
#pragma unroll
    for (int k = 0; k < 8; ++k) r[k] = alpha * acc[k];
    if (beta != 0.0f) {
        uint4 pv = ((const uint4*)(xprev + (size_t)row * WB))[t];
        r[0] += beta * bf2f(pv.x & 0xffffu);
        r[1] += beta * bf2f(pv.x >> 16);
        r[2] += beta * bf2f(pv.y & 0xffffu);
        r[3] += beta * bf2f(pv.y >> 16);
        r[4] += beta * bf2f(pv.z & 0xffffu);
        r[5] += beta * bf2f(pv.z >> 16);
        r[6] += beta * bf2f(pv.w & 0xffffu);
        r[7] += beta * bf2f(pv.w >> 16);
    }
    uint4 o;
    o.x = f2bf(r[0]) | (f2bf(r[1]) << 16);
    o.y = f2bf(r[2]) | (f2bf(r[3]) << 16);
    o.z = f2bf(r[4]) | (f2bf(r[5]) << 16);
    o.w = f2bf(r[6]) | (f2bf(r[7]) << 16);
    ((uint4*)(xout + (size_t)row * WB))[t] = o;
}

// out_acc[bn,0:16] += x_m(bf16) @ Wout_m
__global__ void gemmB_kernel(const unsigned short* __restrict__ x, const float* __restrict__ Wout,
                             float* __restrict__ out_acc, int m) {
    __shared__ float sWo[64 * 16];
    int t = threadIdx.x;   // 128
    for (int i = t; i < 1024; i += 128) {
        int f = i >> 4, u = i & 15;
        sWo[i] = Wout[(f * 5 + m) * 16 + u];
    }
    __syncthreads();
    int b = t & 31, nl = t >> 5;
    int n = blockIdx.x * 4 + nl;
    const unsigned short* xp = x + (size_t)n * WB + b;
    float acc[16];
#pragma unroll
    for (int u = 0; u < 16; ++u) acc[u] = 0.f;
#pragma unroll
    for (int f = 0; f < 64; ++f) {
        float xf = bf2f((unsigned int)xp[f * 32]);
#pragma unroll
        for (int u = 0; u < 16; ++u) acc[u] += xf * sWo[f * 16 + u];
    }
    size_t bn = (size_t)b * NN + n;
    float4* op = (float4*)(out_acc + bn * 16);
#pragma unroll
    for (int g = 0; g < 4; ++g) {
        float4 v = op[g];
        v.x += acc[g * 4 + 0]; v.y += acc[g * 4 + 1];
        v.z += acc[g * 4 + 2]; v.w += acc[g * 4 + 3];
        op[g] = v;
    }
}

// out[i] = -sigmoid(theta_acc[i] + b_lat[u]) * tanh(out_acc[i] + b_lat[u])
__global__ void final_kernel(const float* __restrict__ theta_acc, const float* __restrict__ out_acc,
                             const float* __restrict__ b_lat, float* __restrict__ out) {
    int i = blockIdx.x * blockDim.x + threadIdx.x;   // < B*N*16
    float bl = b_lat[i & 15];
    float tv = theta_acc[i] + bl;
    float ov = out_acc[i] + bl;
    float sg = 1.0f / (1.0f + expf(-tv));
    out[i] = -sg * tanhf(ov);
}

extern "C" void kernel_launch(void* const* d_in, const int* in_sizes, int n_in,
                              void* d_out, int out_size, void* d_ws, size_t ws_size,
                              hipStream_t stream) {
    const float* y      = (const float*)d_in[1];
    const float* Wtheta = (const float*)d_in[2];
    const float* b_lat  = (const float*)d_in[3];
    const float* Whid   = (const float*)d_in[4];
    const float* b_hid  = (const float*)d_in[5];
    const float* Wout   = (const float*)d_in[6];
    const int*   r1     = (const int*)d_in[7];
    const int*   c1     = (const int*)d_in[8];
    const float* v1     = (const float*)d_in[9];
    const int*   r2     = (const int*)d_in[10];
    const int*   c2     = (const int*)d_in[11];
    const float* v2     = (const float*)d_in[12];
    float* out = (float*)d_out;

    // ---- workspace layout ----
    char* ws = (char*)d_ws;
    size_t off = 0;
    auto alloc = [&](size_t bytes) -> char* {
        char* p = ws + off;
        off += (bytes + 255) & ~(size_t)255;
        return p;
    };
    int* rp1   = (int*)alloc(4097 * 4);
    int* rp2   = (int*)alloc(4097 * 4);
    int* cur1  = (int*)alloc(4096 * 4);      // doubles as count buffer
    int* cur2  = (int*)alloc(4096 * 4);
    int* perm1 = (int*)alloc(NNZE * 4);
    int* perm2 = (int*)alloc(NNZE * 4);
    float* theta_acc = (float*)alloc((size_t)BB * NN * 16 * 4);   // 8 MB
    float* out_acc   = (float*)alloc((size_t)BB * NN * 16 * 4);   // 8 MB
    float* hid_t     = (float*)alloc((size_t)NN * WB * 4);        // 32 MB, [n, f*32+b]
    char* un = alloc(3 * (size_t)NN * WB * 2);                    // 48 MB union region
    float* xA0 = (float*)(un);
    float* xA1 = (float*)(un + (size_t)NN * WA * 4);
    float* xA2 = (float*)(un + 2 * (size_t)NN * WA * 4);
    unsigned short* xB0 = (unsigned short*)(un);
    unsigned short* xB1 = (unsigned short*)(un + (size_t)NN * WB * 2);
    unsigned short* xB2 = (unsigned short*)(un + 2 * (size_t)NN * WB * 2);
    if (off > ws_size) return;   // workspace too small: fail loudly (wrong output)

    // ---- zero-init accumulators & histograms ----
    hipMemsetAsync(cur1, 0, 4096 * 4, stream);
    hipMemsetAsync(cur2, 0, 4096 * 4, stream);
    hipMemsetAsync(theta_acc, 0, (size_t)BB * NN * 16 * 4, stream);
    hipMemsetAsync(out_acc,   0, (size_t)BB * NN * 16 * 4, stream);
    hipMemsetAsync(hid_t,     0, (size_t)NN * WB * 4, stream);

    // ---- CSR build for both supports ----
    hist_kernel<<<NNZE / 256, 256, 0, stream>>>(r1, cur1);
    hist_kernel<<<NNZE / 256, 256, 0, stream>>>(r2, cur2);
    scan_kernel<<<1, 256, 0, stream>>>(cur1, rp1, cur1);
    scan_kernel<<<1, 256, 0, stream>>>(cur2, rp2, cur2);
    scatter_kernel<<<NNZE / 256, 256, 0, stream>>>(r1, cur1, perm1);
    scatter_kernel<<<NNZE / 256, 256, 0, stream>>>(r2, cur2, perm2);

    // ---- pass A: F=16 diffusion (shared by theta & hid projections) ----
    transposeA_kernel<<<(NN * WA) / 256, 256, 0, stream>>>(y, xA0);
    gemmA_kernel<<<NN / 4, 128, 0, stream>>>(xA0, Wtheta, Whid, theta_acc, hid_t, 0);
    spmmA_kernel<<<NN, 128, 0, stream>>>(xA0, xA0, xA1, rp1, perm1, c1, v1, 1.f, 0.f);
    gemmA_kernel<<<NN / 4, 128, 0, stream>>>(xA1, Wtheta, Whid, theta_acc, hid_t, 1);
    spmmA_kernel<<<NN, 128, 0, stream>>>(xA1, xA0, xA2, rp1, perm1, c1, v1, 2.f, -1.f);
    gemmA_kernel<<<NN / 4, 128, 0, stream>>>(xA2, Wtheta, Whid, theta_acc, hid_t, 2);
    spmmA_kernel<<<NN, 128, 0, stream>>>(xA0, xA0, xA1, rp2, perm2, c2, v2, 1.f, 0.f);
    gemmA_kernel<<<NN / 4, 128, 0, stream>>>(xA1, Wtheta, Whid, theta_acc, hid_t, 3);
    spmmA_kernel<<<NN, 128, 0, stream>>>(xA1, xA0, xA2, rp2, perm2, c2, v2, 2.f, -1.f);
    gemmA_kernel<<<NN / 4, 128, 0, stream>>>(xA2, Wtheta, Whid, theta_acc, hid_t, 4);

    // ---- pass B: c = tanh(hid + b_hid), F=64 diffusion, W_out projection ----
    actB_kernel<<<(NN * WB) / 256, 256, 0, stream>>>(hid_t, b_hid, xB0);
    gemmB_kernel<<<NN / 4, 128, 0, stream>>>(xB0, Wout, out_acc, 0);
    spmmB_kernel<<<NN, 256, 0, stream>>>(xB0, xB0, xB1, rp1, perm1, c1, v1, 1.f, 0.f);
    gemmB_kernel<<<NN / 4, 128, 0, stream>>>(xB1, Wout, out_acc, 1);
    spmmB_kernel<<<NN, 256, 0, stream>>>(xB1, xB0, xB2, rp1, perm1, c1, v1, 2.f, -1.f);
    gemmB_kernel<<<NN / 4, 128, 0, stream>>>(xB2, Wout, out_acc, 2);
    spmmB_kernel<<<NN, 256, 0, stream>>>(xB0, xB0, xB1, rp2, perm2, c2, v2, 1.f, 0.f);
    gemmB_kernel<<<NN / 4, 128, 0, stream>>>(xB1, Wout, out_acc, 3);
    spmmB_kernel<<<NN, 256, 0, stream>>>(xB1, xB0, xB2, rp2, perm2, c2, v2, 2.f, -1.f);
    gemmB_kernel<<<NN / 4, 128, 0, stream>>>(xB2, Wout, out_acc, 4);

    // ---- epilogue: -sigmoid(theta) * tanh(out) ----
    final_kernel<<<(BB * NN * 16) / 256, 256, 0, stream>>>(theta_acc, out_acc, b_lat, out);
}